// Round 1
// baseline (27766.779 us; speedup 1.0000x reference)
//
#include <hip/hip_runtime.h>
#include <hip/hip_bf16.h>
#include <math.h>

// Problem constants
#define B_    256
#define S_    128
#define EMB_  512
#define H2_   512
#define HID_  1024
#define CTX_  64
#define VOC_  32000
#define TMAX_ 40
#define SOS_  2

__device__ __forceinline__ float4 ld4(const float* p) {
    return *reinterpret_cast<const float4*>(p);
}
__device__ __forceinline__ float sigmoidf_(float x) { return 1.f / (1.f + expf(-x)); }

// ---------------------------------------------------------------------------
// Generic tiled fp32 GEMM: C[m][n] = sum_k A[m][k] * B[n][k]  (+bias[n]) (+addsrc[m][n])
// A-source modes:
//   0: plain row-major A (lda)
//   1: encoder gx gather: m -> (b = m&255, s = s_base + m>>8), row = emb[ids[b*128+s]]
//   2: decoder ctx composite: k<1024 -> Ap[m*1024+k] (hcat), else Ex[m*64 + k-1024] (context_vec)
//   3: decoder emb gather: row = emb[ids[m]]
// ---------------------------------------------------------------------------
template<int BM, int BN, int TM, int TN, int AMODE>
__launch_bounds__(256)
__global__ void gemm_nt(const float* __restrict__ Ap,
                        const int*   __restrict__ ids,
                        const float* __restrict__ Ex,
                        const float* __restrict__ Bp, int ldb, int bofs,
                        const float* __restrict__ bias,
                        const float* __restrict__ addsrc,
                        float* __restrict__ Cp, int ldc,
                        int lda, int K, int s_base)
{
    constexpr int BK = 32;
    static_assert(BM * BK / 4 % 256 == 0, "A staging");
    static_assert(BN * BK / 4 % 256 == 0, "B staging");
    __shared__ float As[BK][BM + 4];
    __shared__ float Bs[BK][BN + 4];
    const int t  = threadIdx.x;
    const int tx = t & 15, ty = t >> 4;
    const int m_base = blockIdx.y * BM;
    const int n_base = blockIdx.x * BN;

    float acc[TM][TN];
#pragma unroll
    for (int i = 0; i < TM; ++i)
#pragma unroll
        for (int j = 0; j < TN; ++j) acc[i][j] = 0.f;

    constexpr int A_PER = BM * BK / 4 / 256;
    constexpr int B_PER = BN * BK / 4 / 256;

    for (int k0 = 0; k0 < K; k0 += BK) {
#pragma unroll
        for (int j = 0; j < A_PER; ++j) {
            int f   = t + j * 256;
            int row = f >> 3;
            int kk  = (f & 7) << 2;
            int m   = m_base + row;
            float4 v;
            if constexpr (AMODE == 0) {
                v = ld4(Ap + (size_t)m * lda + k0 + kk);
            } else if constexpr (AMODE == 1) {
                int bb = m & 255, ss = s_base + (m >> 8);
                int id = ids[bb * S_ + ss];
                v = ld4(Ex + (size_t)id * EMB_ + k0 + kk);
            } else if constexpr (AMODE == 3) {
                int id = ids[m];
                v = ld4(Ex + (size_t)id * EMB_ + k0 + kk);
            } else {  // AMODE == 2
                int k = k0 + kk;
                if (k < HID_) v = ld4(Ap + (size_t)m * HID_ + k);
                else          v = ld4(Ex + (size_t)m * CTX_ + (k - HID_));
            }
            As[kk + 0][row] = v.x; As[kk + 1][row] = v.y;
            As[kk + 2][row] = v.z; As[kk + 3][row] = v.w;
        }
#pragma unroll
        for (int j = 0; j < B_PER; ++j) {
            int f   = t + j * 256;
            int row = f >> 3;
            int kk  = (f & 7) << 2;
            float4 v = ld4(Bp + (size_t)(n_base + row) * ldb + bofs + k0 + kk);
            Bs[kk + 0][row] = v.x; Bs[kk + 1][row] = v.y;
            Bs[kk + 2][row] = v.z; Bs[kk + 3][row] = v.w;
        }
        __syncthreads();
#pragma unroll
        for (int kk = 0; kk < BK; ++kk) {
            float a[TM], b[TN];
            *(float4*)&a[0] = ld4(&As[kk][ty * TM]);
            if constexpr (TM == 8) *(float4*)&a[4] = ld4(&As[kk][ty * TM + 4]);
            *(float4*)&b[0] = ld4(&Bs[kk][tx * TN]);
            if constexpr (TN == 8) *(float4*)&b[4] = ld4(&Bs[kk][tx * TN + 4]);
#pragma unroll
            for (int i = 0; i < TM; ++i)
#pragma unroll
                for (int j = 0; j < TN; ++j) acc[i][j] += a[i] * b[j];
        }
        __syncthreads();
    }
#pragma unroll
    for (int i = 0; i < TM; ++i) {
        int m = m_base + ty * TM + i;
#pragma unroll
        for (int j = 0; j < TN; ++j) {
            int n = n_base + tx * TN + j;
            float v = acc[i][j];
            if (bias)   v += bias[n];
            if (addsrc) v += addsrc[(size_t)m * ldc + n];
            Cp[(size_t)m * ldc + n] = v;
        }
    }
}

// ---------------------------------------------------------------------------
// whh [1536][512] -> whh_t [512][1536] (k-major for coalesced recurrent loads)
// ---------------------------------------------------------------------------
__global__ void transpose_whh(const float* __restrict__ whh, float* __restrict__ out)
{
    int idx = blockIdx.x * 256 + threadIdx.x;     // 512*1536
    int k = idx / 1536, c = idx % 1536;
    out[idx] = whh[(size_t)c * H2_ + k];
}

__global__ void init_dec(float* __restrict__ hdec, int* __restrict__ prev)
{
    int idx = blockIdx.x * 256 + threadIdx.x;     // 262144
    hdec[idx] = 0.f;
    if (idx < B_) prev[idx] = SOS_;
}

// ---------------------------------------------------------------------------
// Encoder recurrence, one 32-step chunk. 64 blocks x 512 threads, block owns
// 4 batch rows; h kept in LDS; whh_t streamed from L2 (3 MB resident).
// Thread t computes gate columns {t, 512+t, 1024+t} -> full GRU combine in regs.
// ---------------------------------------------------------------------------
__launch_bounds__(512)
__global__ void enc_recur(const float* __restrict__ gxbuf,   // [32][256][1536], bih included
                          const float* __restrict__ whh_t,   // [512][1536]
                          const float* __restrict__ bhh,     // [1536]
                          float* __restrict__ hstate,        // [256][512] carry
                          int start_local, int sdir, int first)
{
    __shared__ float hs[4][H2_];
    const int t = threadIdx.x;
    const int row0 = blockIdx.x * 4;
    const float bhr = bhh[t], bhz = bhh[H2_ + t], bhn = bhh[2 * H2_ + t];
#pragma unroll
    for (int r = 0; r < 4; ++r)
        hs[r][t] = first ? 0.f : hstate[(size_t)(row0 + r) * H2_ + t];
    __syncthreads();

    for (int st = 0; st < 32; ++st) {
        int s = start_local + sdir * st;
        const float* gxs = gxbuf + ((size_t)s * B_ + row0) * 1536;
        float aR[4] = {0, 0, 0, 0}, aZ[4] = {0, 0, 0, 0}, aN[4] = {0, 0, 0, 0};
        for (int kb = 0; kb < H2_; kb += 4) {
            float4 hv[4];
#pragma unroll
            for (int r = 0; r < 4; ++r) hv[r] = *(const float4*)&hs[r][kb];
#pragma unroll
            for (int q = 0; q < 4; ++q) {
                const float* wrow = whh_t + (size_t)(kb + q) * 1536;
                float wr = wrow[t], wz = wrow[H2_ + t], wn = wrow[2 * H2_ + t];
#pragma unroll
                for (int r = 0; r < 4; ++r) {
                    float h = ((const float*)&hv[r])[q];
                    aR[r] += h * wr; aZ[r] += h * wz; aN[r] += h * wn;
                }
            }
        }
        float hn[4];
#pragma unroll
        for (int r = 0; r < 4; ++r) {
            const float* g = gxs + (size_t)r * 1536;
            float rg = sigmoidf_(g[t]            + aR[r] + bhr);
            float zg = sigmoidf_(g[H2_ + t]      + aZ[r] + bhz);
            float ng = tanhf    (g[2 * H2_ + t]  + rg * (aN[r] + bhn));
            hn[r] = (1.f - zg) * ng + zg * hs[r][t];
        }
        __syncthreads();
#pragma unroll
        for (int r = 0; r < 4; ++r) hs[r][t] = hn[r];
        __syncthreads();
    }
#pragma unroll
    for (int r = 0; r < 4; ++r)
        hstate[(size_t)(row0 + r) * H2_ + t] = hs[r][t];
}

// ---------------------------------------------------------------------------
// Decoder GRU combine: h = (1-z)*n + z*h  (gi has bih+gctx folded, gh has bhh)
// ---------------------------------------------------------------------------
__global__ void dec_combine(const float* __restrict__ gi, const float* __restrict__ gh,
                            float* __restrict__ hdec)
{
    int idx = blockIdx.x * 256 + threadIdx.x;     // 256*1024
    int b = idx >> 10, u = idx & 1023;
    size_t gb = (size_t)b * 3072;
    float r = sigmoidf_(gi[gb + u]           + gh[gb + u]);
    float z = sigmoidf_(gi[gb + HID_ + u]    + gh[gb + HID_ + u]);
    float n = tanhf    (gi[gb + 2 * HID_ + u] + r * gh[gb + 2 * HID_ + u]);
    hdec[idx] = (1.f - z) * n + z * hdec[idx];
}

// ---------------------------------------------------------------------------
// Per-row argmax (first-index tie-break, matching jnp.argmax) + softmax logsumexp.
// Writes token (as float), log-prob, and prev[] for the next decode step.
// ---------------------------------------------------------------------------
__launch_bounds__(256)
__global__ void argmax_lse(const float* __restrict__ logits,
                           float* __restrict__ out, int* __restrict__ prev, int t)
{
    __shared__ float sv[256];
    __shared__ int   si[256];
    const int b = blockIdx.x, tid = threadIdx.x;
    const float* row = logits + (size_t)b * VOC_;
    float best = -3.4e38f; int bidx = 0;
    for (int i = tid; i < VOC_; i += 256) {
        float v = row[i];
        if (v > best) { best = v; bidx = i; }
    }
    sv[tid] = best; si[tid] = bidx;
    __syncthreads();
    for (int off = 128; off > 0; off >>= 1) {
        if (tid < off) {
            float v2 = sv[tid + off]; int i2 = si[tid + off];
            if (v2 > sv[tid] || (v2 == sv[tid] && i2 < si[tid])) { sv[tid] = v2; si[tid] = i2; }
        }
        __syncthreads();
    }
    float m = sv[0]; int am = si[0];
    __syncthreads();
    float s = 0.f;
    for (int i = tid; i < VOC_; i += 256) s += expf(row[i] - m);
    sv[tid] = s;
    __syncthreads();
    for (int off = 128; off > 0; off >>= 1) {
        if (tid < off) sv[tid] += sv[tid + off];
        __syncthreads();
    }
    if (tid == 0) {
        float sel = 1.f / sv[0];
        float lp  = logf(sel + 1e-12f);
        out[(size_t)b * TMAX_ + t]                 = (float)am;
        out[B_ * TMAX_ + (size_t)b * TMAX_ + t]    = lp;
        prev[b] = am;
    }
}

// ---------------------------------------------------------------------------
extern "C" void kernel_launch(void* const* d_in, const int* in_sizes, int n_in,
                              void* d_out, int out_size, void* d_ws, size_t ws_size,
                              hipStream_t stream)
{
    const int*   ids   = (const int*)  d_in[0];
    const float* cvec  = (const float*)d_in[1];
    const float* emb   = (const float*)d_in[2];
    const float* wih_f = (const float*)d_in[3];
    const float* whh_f = (const float*)d_in[4];
    const float* bih_f = (const float*)d_in[5];
    const float* bhh_f = (const float*)d_in[6];
    const float* wih_b = (const float*)d_in[7];
    const float* whh_b = (const float*)d_in[8];
    const float* bih_b = (const float*)d_in[9];
    const float* bhh_b = (const float*)d_in[10];
    const float* dwih  = (const float*)d_in[11];
    const float* dwhh  = (const float*)d_in[12];
    const float* dbih  = (const float*)d_in[13];
    const float* dbhh  = (const float*)d_in[14];
    const float* wout  = (const float*)d_in[15];
    const float* bout  = (const float*)d_in[16];
    float* out = (float*)d_out;

    // workspace carve (floats). Total ~= 69 MB.
    float* w = (float*)d_ws;
    float* whh_t_f = w;  w += 512 * 1536;            // 786432
    float* whh_t_b = w;  w += 512 * 1536;
    float* gxbuf   = w;  w += 32 * B_ * 1536;        // 12582912 (48 MB, reused for logits)
    float* hcat    = w;  w += 2 * B_ * H2_;          // 262144
    float* hdec    = w;  w += B_ * HID_;             // 262144
    float* gctx    = w;  w += B_ * 3072;             // 786432
    float* gibuf   = w;  w += B_ * 3072;
    float* ghbuf   = w;  w += B_ * 3072;
    int*   prev    = (int*)w;
    float* logits  = gxbuf;                          // encoder finished before decode

    transpose_whh<<<3072, 256, 0, stream>>>(whh_f, whh_t_f);
    transpose_whh<<<3072, 256, 0, stream>>>(whh_b, whh_t_b);
    init_dec<<<1024, 256, 0, stream>>>(hdec, prev);

    // ---------------- encoder: both directions, 4 chunks of 32 steps ----------------
    for (int dir = 0; dir < 2; ++dir) {
        const float* wih = dir ? wih_b : wih_f;
        const float* bih = dir ? bih_b : bih_f;
        const float* bhh = dir ? bhh_b : bhh_f;
        const float* wt  = dir ? whh_t_b : whh_t_f;
        float* hst = hcat + dir * (B_ * H2_);
        for (int c = 0; c < 4; ++c) {
            int s_base = dir ? (96 - c * 32) : (c * 32);
            // gx[s_local][b][1536] = emb[ids] @ wih.T + bih   (M=8192, N=1536, K=512)
            gemm_nt<128, 128, 8, 8, 1><<<dim3(12, 64), 256, 0, stream>>>(
                nullptr, ids, emb, wih, 512, 0, bih, nullptr,
                gxbuf, 1536, 0, 512, s_base);
            enc_recur<<<64, 512, 0, stream>>>(gxbuf, wt, bhh, hst,
                                              dir ? 31 : 0, dir ? -1 : 1, c == 0);
        }
    }

    // gctx[b][3072] = ctx @ dec_wih[:,512:1600].T + bih   (M=256, N=3072, K=1088)
    gemm_nt<64, 64, 4, 4, 2><<<dim3(48, 4), 256, 0, stream>>>(
        hcat, nullptr, cvec, dwih, 1600, 512, dbih, nullptr,
        gctx, 3072, 0, 1088, 0);

    // ---------------- decoder: 40 greedy steps ----------------
    for (int t = 0; t < 40; ++t) {
        // gh = h @ dec_whh.T + bhh   (M=256, N=3072, K=1024)
        gemm_nt<64, 64, 4, 4, 0><<<dim3(48, 4), 256, 0, stream>>>(
            hdec, nullptr, nullptr, dwhh, 1024, 0, dbhh, nullptr,
            ghbuf, 3072, 1024, 1024, 0);
        // gi = emb[prev] @ dec_wih[:,0:512].T + gctx   (M=256, N=3072, K=512)
        gemm_nt<64, 64, 4, 4, 3><<<dim3(48, 4), 256, 0, stream>>>(
            nullptr, prev, emb, dwih, 1600, 0, nullptr, gctx,
            gibuf, 3072, 0, 512, 0);
        dec_combine<<<1024, 256, 0, stream>>>(gibuf, ghbuf, hdec);
        // logits = h @ wout.T + bout   (M=256, N=32000, K=1024)
        gemm_nt<128, 128, 8, 8, 0><<<dim3(250, 2), 256, 0, stream>>>(
            hdec, nullptr, nullptr, wout, 1024, 0, bout, nullptr,
            logits, 32000, 1024, 1024, 0);
        argmax_lse<<<256, 256, 0, stream>>>(logits, out, prev, t);
    }
}

// Round 3
// 17930.820 us; speedup vs baseline: 1.5486x; 1.5486x over previous
//
#include <hip/hip_runtime.h>
#include <hip/hip_bf16.h>
#include <hip/hip_cooperative_groups.h>
#include <math.h>

namespace cg = cooperative_groups;

#define B_    256
#define S_    128
#define EMB_  512
#define H2_   512
#define HID_  1024
#define CTX_  64
#define VOC_  32000
#define TMAX_ 40
#define SOS_  2

typedef unsigned short u16;
typedef __attribute__((ext_vector_type(8))) short short8;
typedef __attribute__((ext_vector_type(4))) float f32x4;

__device__ __forceinline__ float4 ld4(const float* p) {
    return *reinterpret_cast<const float4*>(p);
}
__device__ __forceinline__ float sigmoidf_(float x) { return 1.f / (1.f + expf(-x)); }
__device__ __forceinline__ u16 f2bf(float x) {
    union { float f; unsigned int u; } v; v.f = x;
    unsigned int r = v.u + 0x7FFFu + ((v.u >> 16) & 1u);
    return (u16)(r >> 16);
}
__device__ __forceinline__ unsigned pk2(float a, float b) {
    float2 t; t.x = a; t.y = b;
    __hip_bfloat162 h = __float22bfloat162_rn(t);
    return *reinterpret_cast<unsigned*>(&h);
}
// merge two (value desc, index asc)-ordered top-2 pairs
__device__ __forceinline__ void merge_top2(float& v1, int& i1, float& v2, int& i2,
                                           float ov1, int oi1, float ov2, int oi2)
{
    if (ov1 > v1 || (ov1 == v1 && oi1 < i1)) {
        float tv = v1; int ti = i1;
        v1 = ov1; i1 = oi1;
        if (ov2 > tv || (ov2 == tv && oi2 < ti)) { v2 = ov2; i2 = oi2; }
        else                                     { v2 = tv;  i2 = ti;  }
    } else {
        if (ov1 > v2 || (ov1 == v2 && oi1 < i2)) { v2 = ov1; i2 = oi1; }
    }
}

// ---------------------------------------------------------------------------
// fp32 tiled GEMM: C[m][n] = sum_k A[m][k]*B[n][k] (+bias) (+addsrc)
// AMODE: 0 plain A (lda) | 2 decoder-ctx composite | 3 emb gather via ids[m]
// BGATHER: 0 plain B rows | 1 emb-gather rows: n->(s=n>>8,b=n&255),
//          id=ids[b*S + s_base + sdir*s]
// BIASM: 0 -> bias[n], 1 -> bias[m]
// ---------------------------------------------------------------------------
template<int BM, int BN, int TM, int TN, int AMODE, int BGATHER, int BIASM>
__launch_bounds__(256)
__global__ void gemm_nt(const float* __restrict__ Ap,
                        const int*   __restrict__ ids,
                        const float* __restrict__ Ex,
                        const float* __restrict__ Bp, int ldb, int bofs,
                        const float* __restrict__ bias,
                        const float* __restrict__ addsrc,
                        float* __restrict__ Cp, int ldc,
                        int lda, int K, int s_base, int sdir)
{
    constexpr int BK = 32;
    __shared__ float As[BK][BM + 4];
    __shared__ float Bs[BK][BN + 4];
    const int t  = threadIdx.x;
    const int tx = t & 15, ty = t >> 4;
    const int m_base = blockIdx.y * BM;
    const int n_base = blockIdx.x * BN;

    float acc[TM][TN];
#pragma unroll
    for (int i = 0; i < TM; ++i)
#pragma unroll
        for (int j = 0; j < TN; ++j) acc[i][j] = 0.f;

    constexpr int A_PER = BM * BK / 4 / 256;
    constexpr int B_PER = BN * BK / 4 / 256;

    for (int k0 = 0; k0 < K; k0 += BK) {
#pragma unroll
        for (int j = 0; j < A_PER; ++j) {
            int f   = t + j * 256;
            int row = f >> 3;
            int kk  = (f & 7) << 2;
            int m   = m_base + row;
            float4 v;
            if constexpr (AMODE == 0) {
                v = ld4(Ap + (size_t)m * lda + k0 + kk);
            } else if constexpr (AMODE == 3) {
                int id = ids[m];
                v = ld4(Ex + (size_t)id * EMB_ + k0 + kk);
            } else {  // AMODE == 2
                int k = k0 + kk;
                if (k < HID_) v = ld4(Ap + (size_t)m * HID_ + k);
                else          v = ld4(Ex + (size_t)m * CTX_ + (k - HID_));
            }
            As[kk + 0][row] = v.x; As[kk + 1][row] = v.y;
            As[kk + 2][row] = v.z; As[kk + 3][row] = v.w;
        }
#pragma unroll
        for (int j = 0; j < B_PER; ++j) {
            int f   = t + j * 256;
            int row = f >> 3;
            int kk  = (f & 7) << 2;
            float4 v;
            if constexpr (BGATHER == 1) {
                int n = n_base + row;
                int s = n >> 8, b = n & 255;
                int id = ids[b * S_ + s_base + sdir * s];
                v = ld4(Ex + (size_t)id * EMB_ + k0 + kk);
            } else {
                v = ld4(Bp + (size_t)(n_base + row) * ldb + bofs + k0 + kk);
            }
            Bs[kk + 0][row] = v.x; Bs[kk + 1][row] = v.y;
            Bs[kk + 2][row] = v.z; Bs[kk + 3][row] = v.w;
        }
        __syncthreads();
#pragma unroll
        for (int kk = 0; kk < BK; ++kk) {
            float a[TM], b[TN];
            *(float4*)&a[0] = ld4(&As[kk][ty * TM]);
            if constexpr (TM == 8) *(float4*)&a[4] = ld4(&As[kk][ty * TM + 4]);
            *(float4*)&b[0] = ld4(&Bs[kk][tx * TN]);
            if constexpr (TN == 8) *(float4*)&b[4] = ld4(&Bs[kk][tx * TN + 4]);
#pragma unroll
            for (int i = 0; i < TM; ++i)
#pragma unroll
                for (int j = 0; j < TN; ++j) acc[i][j] += a[i] * b[j];
        }
        __syncthreads();
    }
#pragma unroll
    for (int i = 0; i < TM; ++i) {
        int m = m_base + ty * TM + i;
#pragma unroll
        for (int j = 0; j < TN; ++j) {
            int n = n_base + tx * TN + j;
            float v = acc[i][j];
            if (bias) v += BIASM ? bias[m] : bias[n];
            if (addsrc) v += addsrc[(size_t)m * ldc + n];
            Cp[(size_t)m * ldc + n] = v;
        }
    }
}

// ---------------------------------------------------------------------------
// Cooperative encoder recurrence: 256 blocks x 512 thr, 8 steps per launch.
// Block (dir, ub, rb) owns units [8ub,8ub+8) x rows [128rb,128rb+128).
// whh slice (48KB) LDS-resident; h ping-pongs via hT; grid.sync() per step.
// gxT layout: [col 1536][step 8][batch 256]  (stride 2048 per col)
// ---------------------------------------------------------------------------
__launch_bounds__(512)
__global__ void enc_coop(const float* __restrict__ gxT_f, const float* __restrict__ gxT_b,
                         const float* __restrict__ whh_f, const float* __restrict__ whh_b,
                         const float* __restrict__ bhh_f, const float* __restrict__ bhh_b,
                         float* __restrict__ hT, int nsteps)
{
    cg::grid_group grid = cg::this_grid();
    __shared__ float wlds[8 * 3 * 512];     // 48 KB
    __shared__ float hs[2][128][9];
    const int bid = blockIdx.x;
    const int dir = bid >> 7, blk = bid & 127;
    const int ub = blk >> 1, rb = blk & 1;
    const float* whh = dir ? whh_b : whh_f;
    const float* bhh = dir ? bhh_b : bhh_f;
    const float* gxT = dir ? gxT_b : gxT_f;
    float* hbase = hT + (size_t)dir * (2 * 512 * 256);
    const int t = threadIdx.x;

    for (int i = t * 4; i < 8 * 3 * 512; i += 512 * 4) {
        int ug = i >> 9, k = i & 511;
        int u = ug / 3, g = ug % 3;
        *(float4*)&wlds[i] = ld4(whh + ((size_t)(g * 512 + ub * 8 + u)) * 512 + k);
    }
    const int rl = t & 127;
    const int usub = t >> 7;
    const int r0 = rb * 128;
    const int r = r0 + rl;
    float bh[2][3];
#pragma unroll
    for (int uu = 0; uu < 2; ++uu)
#pragma unroll
        for (int g = 0; g < 3; ++g) bh[uu][g] = bhh[g * 512 + ub * 8 + usub * 2 + uu];
    const int skk = t >> 6;
    const int srr = (t & 63) * 2;
    __syncthreads();

    for (int st = 0; st < nsteps; ++st) {
        const float* hin  = hbase + (st & 1) * (512 * 256);
        float*       hout = hbase + ((st & 1) ^ 1) * (512 * 256);
        {
            float2 v = *(const float2*)(hin + (size_t)skk * 256 + r0 + srr);
            hs[0][srr][skk] = v.x; hs[0][srr + 1][skk] = v.y;
        }
        __syncthreads();
        float acc[2][3] = {{0.f,0.f,0.f},{0.f,0.f,0.f}};
        for (int kt = 0; kt < 64; ++kt) {
            int cur = kt & 1;
            if (kt < 63) {
                float2 v = *(const float2*)(hin + (size_t)((kt + 1) * 8 + skk) * 256 + r0 + srr);
                hs[cur ^ 1][srr][skk] = v.x; hs[cur ^ 1][srr + 1][skk] = v.y;
            }
            const float* hrow = &hs[cur][rl][0];
            float h8[8];
#pragma unroll
            for (int j = 0; j < 8; ++j) h8[j] = hrow[j];
#pragma unroll
            for (int uu = 0; uu < 2; ++uu)
#pragma unroll
                for (int g = 0; g < 3; ++g) {
                    const float* wp = &wlds[((usub * 2 + uu) * 3 + g) * 512 + kt * 8];
                    float4 w0 = *(const float4*)wp, w1 = *(const float4*)(wp + 4);
                    acc[uu][g] += h8[0]*w0.x + h8[1]*w0.y + h8[2]*w0.z + h8[3]*w0.w
                                + h8[4]*w1.x + h8[5]*w1.y + h8[6]*w1.z + h8[7]*w1.w;
                }
            __syncthreads();
        }
#pragma unroll
        for (int uu = 0; uu < 2; ++uu) {
            int ug = ub * 8 + usub * 2 + uu;
            size_t cbase = (size_t)st * 256 + r;
            float gr = gxT[(size_t)(       ug) * 2048 + cbase];
            float gz = gxT[(size_t)( 512 + ug) * 2048 + cbase];
            float gn = gxT[(size_t)(1024 + ug) * 2048 + cbase];
            float hold = hin[(size_t)ug * 256 + r];
            float rg = sigmoidf_(gr + acc[uu][0] + bh[uu][0]);
            float zg = sigmoidf_(gz + acc[uu][1] + bh[uu][1]);
            float ng = tanhf(gn + rg * (acc[uu][2] + bh[uu][2]));
            hout[(size_t)ug * 256 + r] = (1.f - zg) * ng + zg * hold;
        }
        grid.sync();
    }
}

// ---------------------------------------------------------------------------
__global__ void zerof(float* __restrict__ p, int n)
{
    int i = blockIdx.x * 256 + threadIdx.x;
    if (i < n) p[i] = 0.f;
}

__global__ void init_dec(float* __restrict__ hdec, u16* __restrict__ hbf, int* __restrict__ prev)
{
    int i = blockIdx.x * 256 + threadIdx.x;   // 262144
    hdec[i] = 0.f; hbf[i] = 0;
    if (i < B_) prev[i] = SOS_;
}

// hcat (torch h_n.view quirk): hcat[b][k] = h_dir(b>>7)[(2b)&255 + (k>>9)][k&511]
__global__ void hcat_build(const float* __restrict__ hT, float* __restrict__ hcat)
{
    int idx = blockIdx.x * 256 + threadIdx.x; // 262144
    int b = idx >> 10, k = idx & 1023;
    int d = b >> 7;
    int rr = ((2 * b) & 255) + (k >> 9);
    int kk = k & 511;
    hcat[idx] = hT[(size_t)d * (2 * 512 * 256) + (size_t)kk * 256 + rr];
}

__global__ void dec_combine(const float* __restrict__ gi, const float* __restrict__ gh,
                            float* __restrict__ hdec, u16* __restrict__ hbf)
{
    int idx = blockIdx.x * 256 + threadIdx.x;  // 262144
    int b = idx >> 10, u = idx & 1023;
    size_t gb = (size_t)b * 3072;
    float r = sigmoidf_(gi[gb + u]            + gh[gb + u]);
    float z = sigmoidf_(gi[gb + HID_ + u]     + gh[gb + HID_ + u]);
    float n = tanhf    (gi[gb + 2 * HID_ + u] + r * gh[gb + 2 * HID_ + u]);
    float v = (1.f - z) * n + z * hdec[idx];
    hdec[idx] = v;
    hbf[idx] = f2bf(v);
}

// ---------------------------------------------------------------------------
// Fused bf16 MFMA logits + per-row softmax/top2 partials. No logits buffer.
// A: hdec_bf [256][1024] (bf16). B: wout fp32 [32000][1024], converted to
// bf16 during staging. Block = 128 rows x 128 cols. Per row x 64-col half:
// writes (max, sumexp, top2 val/idx) partials. 500 half-tiles per row.
// ---------------------------------------------------------------------------
__launch_bounds__(256)
__global__ void gemm_logits(const u16* __restrict__ A, const float* __restrict__ Wf,
                            const float* __restrict__ bias,
                            float* __restrict__ pmax, float* __restrict__ psum,
                            float* __restrict__ ptv, int* __restrict__ pti)
{
    __shared__ u16 As[128][72];
    __shared__ u16 Bs[128][72];
    const int t = threadIdx.x;
    const int lane = t & 63, wave = t >> 6;
    const int wm = (wave & 1) * 64, wn = (wave >> 1) * 64;
    const int m0 = blockIdx.y * 128, n0 = blockIdx.x * 128;
    f32x4 acc[4][4];
#pragma unroll
    for (int i = 0; i < 4; ++i)
#pragma unroll
        for (int j = 0; j < 4; ++j) acc[i][j] = (f32x4){0.f, 0.f, 0.f, 0.f};
    const int srow = t >> 1, soff = (t & 1) * 32;

    for (int k0 = 0; k0 < 1024; k0 += 64) {
        const float* wr = Wf + (size_t)(n0 + srow) * 1024 + k0 + soff;
#pragma unroll
        for (int q = 0; q < 4; ++q) {
            *(uint4*)&As[srow][soff + q * 8] =
                *(const uint4*)(A + (size_t)(m0 + srow) * 1024 + k0 + soff + q * 8);
            float4 x = ld4(wr + q * 8);
            float4 y = ld4(wr + q * 8 + 4);
            uint4 o;
            o.x = pk2(x.x, x.y); o.y = pk2(x.z, x.w);
            o.z = pk2(y.x, y.y); o.w = pk2(y.z, y.w);
            *(uint4*)&Bs[srow][soff + q * 8] = o;
        }
        __syncthreads();
#pragma unroll
        for (int s = 0; s < 2; ++s) {
            short8 a[4], b[4];
            int j0 = s * 32 + (lane >> 4) * 8;
#pragma unroll
            for (int i = 0; i < 4; ++i) {
                a[i] = *(const short8*)&As[wm + i * 16 + (lane & 15)][j0];
                b[i] = *(const short8*)&Bs[wn + i * 16 + (lane & 15)][j0];
            }
#pragma unroll
            for (int i = 0; i < 4; ++i)
#pragma unroll
                for (int j = 0; j < 4; ++j)
                    acc[i][j] = __builtin_amdgcn_mfma_f32_16x16x32_bf16(a[i], b[j], acc[i][j], 0, 0, 0);
        }
        __syncthreads();
    }

    // ---- fused epilogue: per-row (max, sumexp, top2) over this wave's 64 cols
    const int htile = blockIdx.x * 2 + (wn >> 6);
    float bn[4]; int jx[4];
#pragma unroll
    for (int j = 0; j < 4; ++j) { jx[j] = n0 + wn + j * 16 + (lane & 15); bn[j] = bias[jx[j]]; }
#pragma unroll
    for (int i = 0; i < 4; ++i) {
#pragma unroll
        for (int rr = 0; rr < 4; ++rr) {
            float v[4];
#pragma unroll
            for (int j = 0; j < 4; ++j) v[j] = acc[i][j][rr] + bn[j];
            float v1 = v[0], v2 = -3.4e38f; int i1 = jx[0], i2 = 0x7fffffff;
#pragma unroll
            for (int j = 1; j < 4; ++j) {
                if (v[j] > v1)      { v2 = v1; i2 = i1; v1 = v[j]; i1 = jx[j]; }
                else if (v[j] > v2) { v2 = v[j]; i2 = jx[j]; }
            }
#pragma unroll
            for (int mask = 1; mask <= 8; mask <<= 1) {
                float ov1 = __shfl_xor(v1, mask), ov2 = __shfl_xor(v2, mask);
                int   oi1 = __shfl_xor(i1, mask), oi2 = __shfl_xor(i2, mask);
                merge_top2(v1, i1, v2, i2, ov1, oi1, ov2, oi2);
            }
            float rmax = v1;
            float s = 0.f;
#pragma unroll
            for (int j = 0; j < 4; ++j) s += expf(v[j] - rmax);
#pragma unroll
            for (int mask = 1; mask <= 8; mask <<= 1) s += __shfl_xor(s, mask);
            if ((lane & 15) == 0) {
                int row = m0 + wm + i * 16 + (lane >> 4) * 4 + rr;
                size_t base = (size_t)row * 500 + htile;
                pmax[base] = rmax; psum[base] = s;
                ptv[base * 2] = v1; ptv[base * 2 + 1] = v2;
                pti[base * 2] = i1; pti[base * 2 + 1] = i2;
            }
        }
    }
}

// ---------------------------------------------------------------------------
// Per-row combine of 500 half-tile partials: global max/sumexp, top-8 from
// 1000 candidates, exact fp32 rescore (first-index tie-break), token + lp.
// ---------------------------------------------------------------------------
__launch_bounds__(256)
__global__ void dec_reduce(const float* __restrict__ pmax, const float* __restrict__ psum,
                           const float* __restrict__ ptv, const int* __restrict__ pti,
                           const float* __restrict__ hdec, const float* __restrict__ wout,
                           const float* __restrict__ bout,
                           float* __restrict__ out, int* __restrict__ prev, int tstep)
{
    __shared__ float sv[256]; __shared__ int sti[256]; __shared__ int ssl[256];
    __shared__ float cvv[1000]; __shared__ int cii[1000];
    __shared__ float c8v[8]; __shared__ int c8i[8]; __shared__ float c8e[8];
    const int b = blockIdx.x, tid = threadIdx.x;
    const float* pm = pmax + (size_t)b * 500;
    const float* ps = psum + (size_t)b * 500;

    float m = -3.4e38f;
    for (int i = tid; i < 500; i += 256) m = fmaxf(m, pm[i]);
    sv[tid] = m; __syncthreads();
    for (int off = 128; off; off >>= 1) { if (tid < off) sv[tid] = fmaxf(sv[tid], sv[tid + off]); __syncthreads(); }
    float gmax = sv[0]; __syncthreads();

    float s = 0.f;
    for (int i = tid; i < 500; i += 256) s += ps[i] * expf(pm[i] - gmax);
    sv[tid] = s; __syncthreads();
    for (int off = 128; off; off >>= 1) { if (tid < off) sv[tid] += sv[tid + off]; __syncthreads(); }
    float gsum = sv[0]; __syncthreads();

    for (int i = tid; i < 1000; i += 256) { cvv[i] = ptv[(size_t)b * 1000 + i]; cii[i] = pti[(size_t)b * 1000 + i]; }
    __syncthreads();

    for (int c = 0; c < 8; ++c) {
        float bv = -3.4e38f; int bi = 0x7fffffff, bs = 0;
        for (int i = tid; i < 1000; i += 256) {
            float v = cvv[i]; int ix = cii[i];
            if (v > bv || (v == bv && ix < bi)) { bv = v; bi = ix; bs = i; }
        }
        sv[tid] = bv; sti[tid] = bi; ssl[tid] = bs; __syncthreads();
        for (int off = 128; off; off >>= 1) {
            if (tid < off) {
                if (sv[tid + off] > sv[tid] ||
                    (sv[tid + off] == sv[tid] && sti[tid + off] < sti[tid])) {
                    sv[tid] = sv[tid + off]; sti[tid] = sti[tid + off]; ssl[tid] = ssl[tid + off];
                }
            }
            __syncthreads();
        }
        if (tid == 0) { c8v[c] = sv[0]; c8i[c] = sti[0]; cvv[ssl[0]] = -3.4e38f; }
        __syncthreads();
    }

    {   // exact fp32 rescore, 2 candidates per wave
        int lane = tid & 63, wv = tid >> 6;
        const float* hr = hdec + (size_t)b * HID_;
        for (int c = wv; c < 8; c += 4) {
            const float* wr = wout + (size_t)c8i[c] * HID_;
            float a = 0.f;
            for (int k = lane * 4; k < HID_; k += 256) {
                float4 x = ld4(hr + k), y = ld4(wr + k);
                a += x.x * y.x + x.y * y.y + x.z * y.z + x.w * y.w;
            }
#pragma unroll
            for (int off = 32; off; off >>= 1) a += __shfl_down(a, off);
            if (lane == 0) c8e[c] = a + bout[c8i[c]];
        }
    }
    __syncthreads();

    if (tid == 0) {
        float bv = c8e[0]; int bi = c8i[0]; float av = c8v[0];
        for (int c = 1; c < 8; ++c)
            if (c8e[c] > bv || (c8e[c] == bv && c8i[c] < bi)) { bv = c8e[c]; bi = c8i[c]; av = c8v[c]; }
        float p = expf(av - gmax) / gsum;
        float lp = logf(p + 1e-12f);
        out[(size_t)b * TMAX_ + tstep] = (float)bi;
        out[B_ * TMAX_ + (size_t)b * TMAX_ + tstep] = lp;
        prev[b] = bi;
    }
}

// ---------------------------------------------------------------------------
extern "C" void kernel_launch(void* const* d_in, const int* in_sizes, int n_in,
                              void* d_out, int out_size, void* d_ws, size_t ws_size,
                              hipStream_t stream)
{
    const int*   ids   = (const int*)  d_in[0];
    const float* cvec  = (const float*)d_in[1];
    const float* emb   = (const float*)d_in[2];
    const float* wih_f = (const float*)d_in[3];
    const float* whh_f = (const float*)d_in[4];
    const float* bih_f = (const float*)d_in[5];
    const float* bhh_f = (const float*)d_in[6];
    const float* wih_b = (const float*)d_in[7];
    const float* whh_b = (const float*)d_in[8];
    const float* bih_b = (const float*)d_in[9];
    const float* bhh_b = (const float*)d_in[10];
    const float* dwih  = (const float*)d_in[11];
    const float* dwhh  = (const float*)d_in[12];
    const float* dbih  = (const float*)d_in[13];
    const float* dbhh  = (const float*)d_in[14];
    const float* wout  = (const float*)d_in[15];
    const float* bout  = (const float*)d_in[16];
    float* out = (float*)d_out;

    // workspace carve (floats); total ~= 42.4 MB (round 1 proved >= 68 MB works)
    float* w      = (float*)d_ws;
    float* gxT_f  = w;                         // 3,145,728
    float* gxT_b  = w + 3145728;               // 3,145,728
    float* hT     = w + 6291456;               // 524,288
    float* hcat   = w + 6815744;               // 262,144
    float* hdec   = w + 7077888;               // 262,144
    float* gctx   = w + 7340032;               // 786,432
    float* gibuf  = w + 8126464;               // 786,432
    float* ghbuf  = w + 8912896;               // 786,432
    u16*   hdecb  = (u16*)(w + 9699328);       // 131,072 f
    float* pmax   = w + 9830400;               // 128,000
    float* psum   = w + 9958400;               // 128,000
    float* ptv    = w + 10086400;              // 256,000
    int*   pti    = (int*)(w + 10342400);      // 256,000
    int*   prev   = (int*)(w + 10598400);      // 256

    zerof<<<2048, 256, 0, stream>>>(hT, 524288);
    init_dec<<<1024, 256, 0, stream>>>(hdec, hdecb, prev);

    // ---------------- encoder: 16 chunks x 8 steps, both dirs concurrent ----------------
    for (int c = 0; c < 16; ++c) {
        // gxT[col][s][b] = wih @ emb[ids]^T + bih[col]   (M=1536, N=2048, K=512)
        gemm_nt<128, 128, 8, 8, 0, 1, 1><<<dim3(16, 12), 256, 0, stream>>>(
            wih_f, ids, emb, nullptr, 0, 0, bih_f, nullptr,
            gxT_f, 2048, 512, 512, 8 * c, 1);
        gemm_nt<128, 128, 8, 8, 0, 1, 1><<<dim3(16, 12), 256, 0, stream>>>(
            wih_b, ids, emb, nullptr, 0, 0, bih_b, nullptr,
            gxT_b, 2048, 512, 512, 127 - 8 * c, -1);
        int nsteps = 8;
        void* args[] = { &gxT_f, &gxT_b, &whh_f, &whh_b, &bhh_f, &bhh_b, &hT, &nsteps };
        hipLaunchCooperativeKernel(reinterpret_cast<void*>(enc_coop),
                                   dim3(256), dim3(512), args, 0, stream);
    }

    hcat_build<<<1024, 256, 0, stream>>>(hT, hcat);

    // gctx[b][3072] = [hcat|cvec] @ dec_wih[:,512:1600]^T + dbih
    gemm_nt<64, 64, 4, 4, 2, 0, 0><<<dim3(48, 4), 256, 0, stream>>>(
        hcat, nullptr, cvec, dwih, 1600, 512, dbih, nullptr,
        gctx, 3072, 1024, 1088, 0, 0);

    // ---------------- decoder: 40 greedy steps ----------------
    for (int t = 0; t < TMAX_; ++t) {
        gemm_nt<64, 64, 4, 4, 0, 0, 0><<<dim3(48, 4), 256, 0, stream>>>(
            hdec, nullptr, nullptr, dwhh, 1024, 0, dbhh, nullptr,
            ghbuf, 3072, 1024, 1024, 0, 0);
        gemm_nt<64, 64, 4, 4, 3, 0, 0><<<dim3(48, 4), 256, 0, stream>>>(
            nullptr, prev, emb, dwih, 1600, 0, nullptr, gctx,
            gibuf, 3072, 0, 512, 0, 0);
        dec_combine<<<1024, 256, 0, stream>>>(gibuf, ghbuf, hdec, hdecb);
        gemm_logits<<<dim3(250, 2), 256, 0, stream>>>(hdecb, wout, bout,
                                                      pmax, psum, ptv, pti);
        dec_reduce<<<256, 256, 0, stream>>>(pmax, psum, ptv, pti,
                                            hdec, wout, bout, out, prev, t);
    }
}